// Round 2
// baseline (1574.309 us; speedup 1.0000x reference)
//
#include <hip/hip_runtime.h>
#include <hip/hip_bf16.h>
#include <math.h>

typedef __attribute__((ext_vector_type(4))) float f32x4;
typedef __attribute__((ext_vector_type(8))) __bf16 bf16x8;
typedef __attribute__((ext_vector_type(8))) short short8;
typedef __attribute__((ext_vector_type(4))) unsigned short us4;
typedef __attribute__((ext_vector_type(8))) unsigned short us8;

#define B_    16
#define SEQ_  197
#define TOK_  3152      // 16*197
#define HID_  768
#define MPAD_ 3200      // padded token rows
#define NP_   3136      // 16*196 patch rows
#define DFF_  3072
#define PSZ_  (MPAD_ * HID_)   // one partial buffer, elements (bf16)
#define QKVP_ 14336            // per-(b,h) plane: 224*64 shorts
#define BHN_  192              // 16*12

__device__ __forceinline__ unsigned short f2bf(float x) {
  union { float f; unsigned int u; } v; v.f = x;
  unsigned int r = v.u + 0x7fffu + ((v.u >> 16) & 1u);
  return (unsigned short)(r >> 16);
}

__device__ __forceinline__ float bf2f(unsigned short u) {
  union { unsigned int i; float f; } v; v.i = ((unsigned int)u) << 16; return v.f;
}

__device__ __forceinline__ f32x4 mfma16(bf16x8 a, bf16x8 b, f32x4 c) {
  return __builtin_amdgcn_mfma_f32_16x16x32_bf16(a, b, c, 0, 0, 0);
}

__device__ __forceinline__ void cp16(const void* g, void* l) {
  __builtin_amdgcn_global_load_lds((__attribute__((address_space(1))) void*)(g),
                                   (__attribute__((address_space(3))) void*)(l),
                                   16, 0, 0);
}

// fast gelu: x*sigmoid(x*(1.59577+0.0713548*x^2))
__device__ __forceinline__ float gelu_f(float x) {
  float y = x * (1.5957691216f + 0.0713548162f * x * x);
  float e = __expf(y);
  float r = 1.0f / (1.0f + e);     // e=inf -> r=0 -> g=x ; e=0 -> r=1 -> g=0
  return x - x * r;
}

// convert chunk c (8 floats) of s into d
__device__ __forceinline__ void conv8(const float* __restrict__ s, unsigned short* __restrict__ d, int c) {
  const float* sp = s + (size_t)c * 8;
  f32x4 v0 = *(const f32x4*)sp;
  f32x4 v1 = *(const f32x4*)(sp + 4);
  us8 o;
  o[0] = f2bf(v0[0]); o[1] = f2bf(v0[1]); o[2] = f2bf(v0[2]); o[3] = f2bf(v0[3]);
  o[4] = f2bf(v1[0]); o[5] = f2bf(v1[1]); o[6] = f2bf(v1[2]); o[7] = f2bf(v1[3]);
  *(us8*)(d + (size_t)c * 8) = o;
}

// ---------------- fused patchify + cls + wmap-conv + (big) layer-0 MLP weight conv
// blocks [0,2400): patchify  [2400,2448): cls  [2448,2736): wmap conv (73728 chunks)
// blocks [2736,5040): layer-0 w1/w2 conv (1152 blocks each, 294912 chunks)
__global__ __launch_bounds__(256) void patchcls_kernel(const float* __restrict__ img,
                                                       unsigned short* __restrict__ Pb,
                                                       const float* __restrict__ ct,
                                                       const float* __restrict__ pos,
                                                       float* __restrict__ X,
                                                       const float* __restrict__ wmap,
                                                       unsigned short* __restrict__ Wmb,
                                                       const float* __restrict__ cw1,
                                                       unsigned short* __restrict__ cd1,
                                                       const float* __restrict__ cw2,
                                                       unsigned short* __restrict__ cd2) {
  int bid = blockIdx.x;
  if (bid >= 2736) {          // layer-0 MLP weights
    int bb = bid - 2736;
    const float* s; unsigned short* d;
    if (bb < 1152) { s = cw1; d = cd1; } else { s = cw2; d = cd2; bb -= 1152; }
    conv8(s, d, bb * 256 + threadIdx.x);
    return;
  }
  if (bid >= 2448) {          // w_map conv
    int c = (bid - 2448) * 256 + threadIdx.x;
    conv8(wmap, Wmb, c);
    return;
  }
  if (bid >= 2400) {          // cls rows
    int j = (bid - 2400) * 256 + threadIdx.x;
    if (j < B_ * HID_) {
      int b = j / HID_, t = j - b * HID_;
      X[(size_t)b * SEQ_ * HID_ + t] = ct[t] + pos[t];
    }
    return;
  }
  int gid = bid * 256 + threadIdx.x;              // 3200*192 total
  int m = gid / 192;
  int j4 = (gid - m * 192) * 4;
  us4 o;
  if (m < NP_) {
    int n = m / 196, p = m - n * 196;
    int pi = p / 14, pj = p - pi * 14;
    int c = j4 >> 8, rem = j4 & 255, ph = rem >> 4, pw = rem & 15;
    const float* src = img + (((size_t)(n * 3 + c) * 224 + pi * 16 + ph) * 224 + pj * 16 + pw);
    f32x4 v = *(const f32x4*)src;
    o[0] = f2bf(v[0]); o[1] = f2bf(v[1]); o[2] = f2bf(v[2]); o[3] = f2bf(v[3]);
  } else {
    o[0] = 0; o[1] = 0; o[2] = 0; o[3] = 0;
  }
  *(us4*)(Pb + (size_t)m * HID_ + j4) = o;
}

// ---------------- standalone fp32 -> bf16 conversion (fallback path only)
__global__ __launch_bounds__(256) void convw_kernel(const float* __restrict__ s1, unsigned short* __restrict__ d1,
                                                    const float* __restrict__ s2, unsigned short* __restrict__ d2,
                                                    int nchunks) {
  int half = gridDim.x >> 1;
  int b = blockIdx.x;
  const float* s; unsigned short* d;
  if (b < half) { s = s1; d = d1; } else { s = s2; d = d2; b -= half; }
  int c = b * 256 + threadIdx.x;
  if (c >= nchunks) return;
  conv8(s, d, c);
}

// ---------------- embed GEMM (BT form): 64x64-tile structure, EPI=embed
__global__ __launch_bounds__(256) void gemm_embed(const unsigned short* __restrict__ A,
                                                  const unsigned short* __restrict__ Bw,
                                                  const float* __restrict__ bias,
                                                  const float* __restrict__ pos,
                                                  float* __restrict__ Xout) {
  constexpr int MI = 2, NJ = 2, BM = 64, BN = 64;
  __shared__ unsigned short As[BM * 64];
  __shared__ unsigned short Bs[BN * 64];
  const int tid = threadIdx.x;
  const int w = tid >> 6, lane = tid & 63;
  const int lr = lane & 15, kg = lane >> 4;
  int bid = blockIdx.x;
  int cpx = gridDim.x >> 3;
  int swz = (bid & 7) * cpx + (bid >> 3);
  const int by = swz / 12, bx = swz - by * 12;
  const int m0 = by * BM, n0 = bx * BN;
  const int wr = w >> 1, wc = w & 1;
  const f32x4 z4 = {0.f, 0.f, 0.f, 0.f};
  f32x4 acc[MI][NJ];
#pragma unroll
  for (int i = 0; i < MI; ++i)
#pragma unroll
    for (int j = 0; j < NJ; ++j) acc[i][j] = z4;
  for (int k0 = 0; k0 < 768; k0 += 64) {
#pragma unroll
    for (int is = 0; is < MI; ++is) {
      int chunk = is * 256 + tid;
      int row = chunk >> 3, cc = (chunk & 7) * 8;
      cp16(A + (size_t)(m0 + row) * 768 + k0 + cc, As + is * 2048 + w * 512);
    }
#pragma unroll
    for (int is = 0; is < NJ; ++is) {
      int chunk = is * 256 + tid;
      int row = chunk >> 3, cc = (chunk & 7) * 8;
      cp16(Bw + (size_t)(n0 + row) * 768 + k0 + cc, Bs + is * 2048 + w * 512);
    }
    __syncthreads();
#pragma unroll
    for (int kk = 0; kk < 64; kk += 32) {
      bf16x8 af[MI], bfr[NJ];
#pragma unroll
      for (int i = 0; i < MI; ++i)
        af[i] = *(const bf16x8*)&As[(wr * (BM / 2) + i * 16 + lr) * 64 + kk + kg * 8];
#pragma unroll
      for (int j = 0; j < NJ; ++j)
        bfr[j] = *(const bf16x8*)&Bs[(wc * (BN / 2) + j * 16 + lr) * 64 + kk + kg * 8];
#pragma unroll
      for (int i = 0; i < MI; ++i)
#pragma unroll
        for (int j = 0; j < NJ; ++j)
          acc[i][j] = mfma16(af[i], bfr[j], acc[i][j]);
    }
    __syncthreads();
  }
#pragma unroll
  for (int i = 0; i < MI; ++i) {
    int mbase = m0 + wr * (BM / 2) + i * 16 + kg * 4;
#pragma unroll
    for (int j = 0; j < NJ; ++j) {
      int col = n0 + wc * (BN / 2) + j * 16 + lr;
#pragma unroll
      for (int qr = 0; qr < 4; ++qr) {
        int m = mbase + qr;
        if (m < NP_) {
          int nimg = m / 196;
          int tok = m + nimg + 1;
          int prow = m - nimg * 196 + 1;
          Xout[(size_t)tok * HID_ + col] = acc[i][j][qr] + bias[col] + pos[(size_t)prow * HID_ + col];
        }
      }
    }
  }
}

// ---------------- 128x128-tile 4-wave pipelined GEMM, BK=32, 4 LDS buffers (64KB -> 2 blocks/CU)
// wave tile 64x64 (acc 4x4): 8KB LDS reads per 16 MFMA (32 FLOP/B, balanced vs 16 before).
// LDS XOR-swizzle: 16B unit u -> u ^ ((row>>1)&3), applied as pre-swizzled GLOBAL source
// (global_load_lds dest must stay linear) + swizzled ds_read offset. 8-way -> 2-way (free).
template<int EPI, int NT>
__global__ __launch_bounds__(256, 2) void gemm4b(const unsigned short* __restrict__ A,
                                                 const unsigned short* __restrict__ Bw,
                                                 int ldk, int gx, int gy,
                                                 const float* __restrict__ bias,
                                                 unsigned short* __restrict__ Pout,
                                                 unsigned short* __restrict__ Hout) {
  __shared__ unsigned short lds4[32768];   // 4 buffers x (A 4096 + B 4096 shorts) = 64 KiB
  const int tid = threadIdx.x;
  const int wid = tid >> 6, lane = tid & 63;
  const int lr = lane & 15, kg = lane >> 4;
  const int wm = wid >> 1, wn = wid & 1;           // 2 x 2 waves; wave owns 64 x 64 output
  const int nwg = gridDim.x;
  const int q = nwg >> 3, r = nwg & 7;
  const int xcd = blockIdx.x & 7, idx = blockIdx.x >> 3;
  const int wgid = (xcd < r ? xcd * (q + 1) : r * (q + 1) + (xcd - r) * q) + idx;
  const int bx = wgid % gx;
  const int rest = wgid / gx;
  const int by = rest % gy;
  const int z = rest / gy;
  const int m0 = by * 128, n0 = bx * 128;
  const unsigned short* Abase = A + (size_t)m0 * ldk + z * (NT * 32);
  const unsigned short* Bbase = Bw + (size_t)n0 * ldk + z * (NT * 32);

  // staging: 2 issues per matrix per tile; chunk c = t*256+tid; row=c>>2, 16B-unit u=c&3.
  // LDS dst linear (row*4+u); global source column pre-swizzled: u ^ ((row>>1)&3).
  const int r0 = tid >> 2, u0 = tid & 3;
  const int r1 = 64 + r0;                          // (256+tid)>>2
  const int sk0 = ((u0 ^ ((r0 >> 1) & 3)) * 8);
  const int sk1 = ((u0 ^ ((r1 >> 1) & 3)) * 8);
  const int d0 = wid * 512;                        // wave-uniform LDS dst (shorts), t=0
  const int d1 = 2048 + wid * 512;                 // t=1

  // prologue: issue tiles 0,1,2 (12 cp16/thread outstanding)
#pragma unroll
  for (int t = 0; t < 3; ++t) {
    unsigned short* lb = lds4 + t * 8192;
    cp16(Abase + (size_t)r0 * ldk + sk0 + t * 32, lb + d0);
    cp16(Abase + (size_t)r1 * ldk + sk1 + t * 32, lb + d1);
    cp16(Bbase + (size_t)r0 * ldk + sk0 + t * 32, lb + 4096 + d0);
    cp16(Bbase + (size_t)r1 * ldk + sk1 + t * 32, lb + 4096 + d1);
  }

  // per-lane swizzled fragment-read offsets (shorts), hoisted
  int offA[4], offB[4];
#pragma unroll
  for (int i = 0; i < 4; ++i) {
    int ra_ = wm * 64 + i * 16 + lr;
    offA[i] = ra_ * 32 + ((kg ^ ((ra_ >> 1) & 3)) * 8);
    int rb_ = wn * 64 + i * 16 + lr;
    offB[i] = rb_ * 32 + ((kg ^ ((rb_ >> 1) & 3)) * 8);
  }

  const f32x4 z4 = {0.f, 0.f, 0.f, 0.f};
  f32x4 acc[4][4];
#pragma unroll
  for (int i = 0; i < 4; ++i)
#pragma unroll
    for (int j = 0; j < 4; ++j) acc[i][j] = z4;

#pragma unroll 1
  for (int k = 0; k < NT; ++k) {
    // gate: tile k resident; tiles k+1,k+2 (8 loads/thread) may stay in flight
    asm volatile("s_waitcnt vmcnt(8)" ::: "memory");
    __builtin_amdgcn_s_barrier();
    __builtin_amdgcn_sched_barrier(0);
    const unsigned short* lp = lds4 + (k & 3) * 8192;
    const int tn = k + 3;
    const int ts = (tn >= NT) ? tn - NT : tn;      // wrapped tail prefetch (harmless reissue)
    unsigned short* tb = lds4 + (tn & 3) * 8192;   // == (k-1)&3: readers done before this gate
    bf16x8 af[4], bfr[4];
#pragma unroll
    for (int i = 0; i < 4; ++i)
      af[i] = *(const bf16x8*)(lp + offA[i]);
#pragma unroll
    for (int j = 0; j < 4; ++j)
      bfr[j] = *(const bf16x8*)(lp + 4096 + offB[j]);
    cp16(Abase + (size_t)r0 * ldk + sk0 + ts * 32, tb + d0);
    cp16(Abase + (size_t)r1 * ldk + sk1 + ts * 32, tb + d1);
    cp16(Bbase + (size_t)r0 * ldk + sk0 + ts * 32, tb + 4096 + d0);
    cp16(Bbase + (size_t)r1 * ldk + sk1 + ts * 32, tb + 4096 + d1);
    __builtin_amdgcn_s_barrier();
    __builtin_amdgcn_s_setprio(1);
#pragma unroll
    for (int i = 0; i < 4; ++i)
#pragma unroll
      for (int j = 0; j < 4; ++j) acc[i][j] = mfma16(af[i], bfr[j], acc[i][j]);
    __builtin_amdgcn_s_setprio(0);
    // next iteration's gate barrier closes this tile
  }

  // epilogue
#pragma unroll
  for (int i = 0; i < 4; ++i) {
    int mbase = m0 + wm * 64 + i * 16 + kg * 4;
#pragma unroll
    for (int j = 0; j < 4; ++j) {
      int col = n0 + wn * 64 + j * 16 + lr;
      float bv = (EPI == 1) ? bias[col] : 0.f;
#pragma unroll
      for (int qr = 0; qr < 4; ++qr) {
        int m = mbase + qr;
        if (m < TOK_) {
          float v = acc[i][j][qr];
          if (EPI == 1) {
            Hout[(size_t)m * 3072 + col] = f2bf(gelu_f(v + bv));
          } else {
            Pout[(size_t)z * PSZ_ + (size_t)m * 768 + col] = f2bf(v);
          }
        }
      }
    }
  }
}

// ---------------- LayerNorm; MODE 0: plain  2: X+=P0..P1(bf16)+pb ; writes Y bf16
// blocks >= 800 (if launched): convert cw1->cd1 (1152 blocks) then cw2->cd2 (1152 blocks)
template<int MODE>
__global__ __launch_bounds__(256) void ln_kernel(float* __restrict__ X,
                                                 const unsigned short* __restrict__ P, const float* __restrict__ pb,
                                                 const float* __restrict__ gw, const float* __restrict__ gb,
                                                 unsigned short* __restrict__ Y,
                                                 const float* __restrict__ cw1, unsigned short* __restrict__ cd1,
                                                 const float* __restrict__ cw2, unsigned short* __restrict__ cd2) {
  int bb = (int)blockIdx.x - 800;
  if (bb >= 0) {              // weight-conversion blocks (next layer's w1/w2)
    const float* s; unsigned short* d;
    if (bb < 1152) { s = cw1; d = cd1; } else { s = cw2; d = cd2; bb -= 1152; }
    conv8(s, d, bb * 256 + threadIdx.x);
    return;
  }
  int row = blockIdx.x * 4 + (threadIdx.x >> 6);
  int lane = threadIdx.x & 63;
  if (row >= MPAD_) return;
  size_t base = (size_t)row * HID_;
  if (row >= TOK_) {
    us4 zz; zz[0] = 0; zz[1] = 0; zz[2] = 0; zz[3] = 0;
#pragma unroll
    for (int i = 0; i < 3; ++i) *(us4*)(Y + base + i * 256 + lane * 4) = zz;
    return;
  }
  f32x4 xv[3];
  float s1 = 0.f, s2 = 0.f;
#pragma unroll
  for (int i = 0; i < 3; ++i) {
    int cb = i * 256 + lane * 4;
    f32x4 v = *(const f32x4*)(X + base + cb);
    if (MODE == 2) {
      const unsigned short* pp = P + base + cb;
      us4 p0 = *(const us4*)(pp);
      us4 p1 = *(const us4*)(pp + PSZ_);
      f32x4 bb2 = *(const f32x4*)(pb + cb);
#pragma unroll
      for (int e = 0; e < 4; ++e)
        v[e] += bf2f(p0[e]) + bf2f(p1[e]) + bb2[e];
      *(f32x4*)(X + base + cb) = v;
    }
    xv[i] = v;
    s1 += v[0] + v[1] + v[2] + v[3];
    s2 += v[0] * v[0] + v[1] * v[1] + v[2] * v[2] + v[3] * v[3];
  }
#pragma unroll
  for (int d = 1; d < 64; d <<= 1) {
    s1 += __shfl_xor(s1, d);
    s2 += __shfl_xor(s2, d);
  }
  float mu = s1 * (1.f / 768.f);
  float var = s2 * (1.f / 768.f) - mu * mu;
  float rs = rsqrtf(var + 1e-5f);
#pragma unroll
  for (int i = 0; i < 3; ++i) {
    int cb = i * 256 + lane * 4;
    us4 o;
#pragma unroll
    for (int e = 0; e < 4; ++e)
      o[e] = f2bf((xv[i][e] - mu) * rs * gw[cb + e] + gb[cb + e]);
    *(us4*)(Y + base + cb) = o;
  }
}

// ---------------- final split-K reduce: X[m] += P0..P1(bf16) + b2   (after layer 11)
__global__ __launch_bounds__(256) void redfin_kernel(float* __restrict__ X, const unsigned short* __restrict__ P,
                                                     const float* __restrict__ b2) {
  int i = blockIdx.x * 256 + threadIdx.x;     // TOK_*192
  if (i >= TOK_ * 192) return;
  int m = i / 192, c4 = (i - m * 192) * 4;
  size_t off = (size_t)m * HID_ + c4;
  f32x4 v = *(const f32x4*)(X + off);
  const unsigned short* pp = P + off;
  us4 p0 = *(const us4*)(pp);
  us4 p1 = *(const us4*)(pp + PSZ_);
  f32x4 bb = *(const f32x4*)(b2 + c4);
#pragma unroll
  for (int e = 0; e < 4; ++e)
    v[e] += bf2f(p0[e]) + bf2f(p1[e]) + bb[e];
  *(f32x4*)(X + off) = v;
}

// ---------------- load 64x64 fp32 weight as bf16 B-fragments (8 x bf16x8 per lane)
__device__ __forceinline__ void loadw_frags(const float* __restrict__ W, int lr, int kg, bf16x8* wf) {
#pragma unroll
  for (int j = 0; j < 4; ++j)
#pragma unroll
    for (int kk = 0; kk < 2; ++kk) {
      const float* wp = W + (j * 16 + lr) * 64 + kk * 32 + kg * 8;
      f32x4 w0 = *(const f32x4*)wp;
      f32x4 w1 = *(const f32x4*)(wp + 4);
      short8 t;
      t[0] = (short)f2bf(w0[0]); t[1] = (short)f2bf(w0[1]); t[2] = (short)f2bf(w0[2]); t[3] = (short)f2bf(w0[3]);
      t[4] = (short)f2bf(w1[0]); t[5] = (short)f2bf(w1[1]); t[6] = (short)f2bf(w1[2]); t[7] = (short)f2bf(w1[3]);
      wf[j * 2 + kk] = __builtin_bit_cast(bf16x8, t);
    }
}

// ---------------- QKV projection: grid 1152 = bh(192) x proj(3) x half(2); 2 waves/block.
// Writes bf16 Q (x0.125) and K row-major [224][64], V transposed [64][224] per (b,h).
// V columns >=197 are zeroed (PV loop reads up to col 223); K rows 197..207 are
// finite-garbage (masked in attn); Q rows >=197 masked at the X write.
__global__ __launch_bounds__(128) void qkvproj_kernel(const unsigned short* __restrict__ Y,
                                                      const float* __restrict__ qw, const float* __restrict__ qb,
                                                      const float* __restrict__ kw, const float* __restrict__ kb,
                                                      const float* __restrict__ vw, const float* __restrict__ vb,
                                                      unsigned short* __restrict__ Qo,
                                                      unsigned short* __restrict__ Ko,
                                                      unsigned short* __restrict__ Vto) {
  const int blk = blockIdx.x;
  const int half = blk & 1;
  const int bp = blk >> 1;                 // 576 = bh*3 + p
  const int p = bp % 3, bh = bp / 3;
  const int b = bh / 12, h = bh - b * 12;
  const int wv = threadIdx.x >> 6, lane = threadIdx.x & 63;
  const int lr = lane & 15, kg = lane >> 4;
  const int ws = half * 2 + wv;            // 0..3 : tile stride-4 owner
  const float* W; const float* bs; unsigned short* out;
  if (p == 0)      { W = qw + h * 4096; bs = qb + h * 64; out = Qo; }
  else if (p == 1) { W = kw + h * 4096; bs = kb + h * 64; out = Ko; }
  else             { W = vw + h * 4096; bs = vb + h * 64; out = Vto; }
  const float scale = (p == 0) ? 0.125f : 1.0f;
  bf16x8 wf[8];
  loadw_frags(W, lr, kg, wf);
  float bj[4];
#pragma unroll
  for (int j = 0; j < 4; ++j) bj[j] = bs[j * 16 + lr];
  out += (size_t)bh * QKVP_;
  const f32x4 z4 = {0.f, 0.f, 0.f, 0.f};
  const short8 zs = {0, 0, 0, 0, 0, 0, 0, 0};
#pragma unroll
  for (int i = 0; i < 4; ++i) {
    int t = ws + 4 * i;
    if (t < 14) {
      int s = t * 16 + lr;
      bf16x8 a0 = __builtin_bit_cast(bf16x8, zs), a1 = a0;
      if (s < SEQ_) {
        const unsigned short* yp = Y + (size_t)(b * SEQ_ + s) * HID_ + h * 64 + kg * 8;
        a0 = *(const bf16x8*)yp;
        a1 = *(const bf16x8*)(yp + 32);
      }
      f32x4 acc[4] = {z4, z4, z4, z4};
#pragma unroll
      for (int j = 0; j < 4; ++j) {
        acc[j] = mfma16(a0, wf[j * 2 + 0], acc[j]);
        acc[j] = mfma16(a1, wf[j * 2 + 1], acc[j]);
      }
      if (p == 2) {
#pragma unroll
        for (int j = 0; j < 4; ++j) {
          us4 pk;
#pragma unroll
          for (int qr = 0; qr < 4; ++qr) {
            int srow = t * 16 + kg * 4 + qr;
            pk[qr] = (srow < SEQ_) ? f2bf(acc[j][qr] + bj[j]) : (unsigned short)0;
          }
          *(us4*)&out[(j * 16 + lr) * 224 + t * 16 + kg * 4] = pk;
        }
      } else {
#pragma unroll
        for (int j = 0; j < 4; ++j)
#pragma unroll
          for (int qr = 0; qr < 4; ++qr) {
            int row = t * 16 + kg * 4 + qr;
            out[row * 64 + j * 16 + lr] = f2bf((acc[j][qr] + bj[j]) * scale);
          }
      }
    }
  }
}

// ---------------- attention: grid 2496 = bh(192) x qtile(13); 1 wave/block, 7.4 KiB LDS.
// Same math as the old fused phase C; K/V read from L2-resident global planes.
__global__ __launch_bounds__(64) void attn_kernel(const unsigned short* __restrict__ Qb,
                                                  const unsigned short* __restrict__ Kb,
                                                  const unsigned short* __restrict__ Vtb,
                                                  float* __restrict__ X) {
  __shared__ unsigned short plds[16 * 232];
  const int blk = blockIdx.x;
  const int qt = blk % 13, bh = blk / 13;
  const int b = bh / 12, h = bh - b * 12;
  const int lane = threadIdx.x;
  const int lr = lane & 15, kg = lane >> 4;
  const f32x4 z4 = {0.f, 0.f, 0.f, 0.f};
  const unsigned short* Qp = Qb + (size_t)bh * QKVP_;
  const unsigned short* Kp = Kb + (size_t)bh * QKVP_;
  const unsigned short* Vp = Vtb + (size_t)bh * QKVP_;
  // zero pad columns 208..223 of P (PV loop kt=6 reads them)
  {
    int rr = lane >> 2, c0 = 208 + (lane & 3) * 4;
    us4 zz; zz[0] = 0; zz[1] = 0; zz[2] = 0; zz[3] = 0;
    *(us4*)&plds[rr * 232 + c0] = zz;
  }
  bf16x8 aq0 = *(const bf16x8*)&Qp[(qt * 16 + lr) * 64 + kg * 8];
  bf16x8 aq1 = *(const bf16x8*)&Qp[(qt * 16 + lr) * 64 + 32 + kg * 8];
  f32x4 s[13];
#pragma unroll
  for (int nt = 0; nt < 13; ++nt) {
    const unsigned short* kp = Kp + (nt * 16 + lr) * 64 + kg * 8;
    bf16x8 b0 = *(const bf16x8*)kp;
    bf16x8 b1 = *(const bf16x8*)(kp + 32);
    f32x4 acc = mfma16(aq0, b0, z4);
    s[nt] = mfma16(aq1, b1, acc);
  }
#pragma unroll
  for (int qr = 0; qr < 4; ++qr) {
    float mx = -1e30f;
#pragma unroll
    for (int nt = 0; nt < 13; ++nt) {
      float v = (nt == 12 && lr >= 5) ? -1e30f : s[nt][qr];
      mx = fmaxf(mx, v);
    }
    mx = fmaxf(mx, __shfl_xor(mx, 1));
    mx = fmaxf(mx, __shfl_xor(mx, 2));
    mx = fmaxf(mx, __shfl_xor(mx, 4));
    mx = fmaxf(mx, __shfl_xor(mx, 8));
    float sum = 0.f;
#pragma unroll
    for (int nt = 0; nt < 13; ++nt) {
      float e = (nt == 12 && lr >= 5) ? 0.f : __expf(s[nt][qr] - mx);
      s[nt][qr] = e;
      sum += e;
    }
    sum += __shfl_xor(sum, 1);
    sum += __shfl_xor(sum, 2);
    sum += __shfl_xor(sum, 4);
    sum += __shfl_xor(sum, 8);
    float inv = 1.f / sum;
#pragma unroll
    for (int nt = 0; nt < 13; ++nt)
      plds[(kg * 4 + qr) * 232 + nt * 16 + lr] = f2bf(s[nt][qr] * inv);
  }
  asm volatile("s_waitcnt lgkmcnt(0)" ::: "memory");
  __builtin_amdgcn_sched_barrier(0);
  f32x4 ao[4] = {z4, z4, z4, z4};
#pragma unroll
  for (int kt = 0; kt < 7; ++kt) {
    bf16x8 pa = *(const bf16x8*)&plds[lr * 232 + kt * 32 + kg * 8];
#pragma unroll
    for (int j = 0; j < 4; ++j) {
      bf16x8 bv = *(const bf16x8*)&Vp[(j * 16 + lr) * 224 + kt * 32 + kg * 8];
      ao[j] = mfma16(pa, bv, ao[j]);
    }
  }
#pragma unroll
  for (int j = 0; j < 4; ++j)
#pragma unroll
    for (int qr = 0; qr < 4; ++qr) {
      int ss = qt * 16 + kg * 4 + qr;
      if (ss < SEQ_) {
        size_t xi = (size_t)(b * SEQ_ + ss) * HID_ + h * 64 + j * 16 + lr;
        X[xi] += ao[j][qr];
      }
    }
}

extern "C" void kernel_launch(void* const* d_in, const int* in_sizes, int n_in,
                              void* d_out, int out_size, void* d_ws, size_t ws_size,
                              hipStream_t stream) {
  const float* images = (const float*)d_in[0];
  const float* w_map  = (const float*)d_in[1];
  const float* b_map  = (const float*)d_in[2];
  const float* ctok   = (const float*)d_in[3];
  const float* pos    = (const float*)d_in[4];
  const float* qw   = (const float*)d_in[5];
  const float* qb   = (const float*)d_in[6];
  const float* kw   = (const float*)d_in[7];
  const float* kb   = (const float*)d_in[8];
  const float* vw   = (const float*)d_in[9];
  const float* vb   = (const float*)d_in[10];
  const float* ln1w = (const float*)d_in[11];
  const float* ln1b = (const float*)d_in[12];
  const float* ln2w = (const float*)d_in[13];
  const float* ln2b = (const float*)d_in[14];
  const float* w1   = (const float*)d_in[15];
  const float* b1   = (const float*)d_in[16];
  const float* w2   = (const float*)d_in[17];
  const float* b2   = (const float*)d_in[18];

  float* X = (float*)d_out;   // residual stream lives in d_out: [16*197][768] fp32

  unsigned short* Y    = (unsigned short*)d_ws;                 // [3200][768] bf16 (also patch buffer)
  unsigned short* Wmb  = Y + (size_t)MPAD_ * HID_;              // 768*768
  unsigned short* Hb   = Wmb + (size_t)768 * 768;               // [3200][3072] bf16
  unsigned short* Pp   = Hb + (size_t)MPAD_ * DFF_;             // 2x [3200][768] bf16 split-K partials
  unsigned short* Wr   = Pp + 2 * (size_t)PSZ_;                 // converted MLP weights

  // Q/K/Vt bf16 planes alias the Hb region (dead between gemm-down(l-1) and gemm-up(l)):
  // 3 * 192 * 14336 shorts = 8,257,536 <= 9,830,400 (Hb size). Stream-ordered, no hazard.
  unsigned short* Qb  = Hb;
  unsigned short* Kb2 = Hb + (size_t)BHN_ * QKVP_;
  unsigned short* Vtb = Hb + 2 * (size_t)BHN_ * QKVP_;

  // big path: all 12 layers' w1+w2 pre-converted (fused into patchcls / ln launches)
  const size_t L1 = (size_t)DFF_ * HID_;          // 2,359,296 per layer
  const size_t need = ((size_t)MPAD_ * HID_ + (size_t)768 * 768 + (size_t)MPAD_ * DFF_ +
                       2 * (size_t)PSZ_ + 24 * L1) * 2;
  const bool big = ws_size >= need;
  unsigned short* W1r = Wr;
  unsigned short* W2r = Wr + (big ? 12 * L1 : L1);

  // ---- prologue: patchify + cls + wmap conv + (big) layer-0 MLP weight conv
  patchcls_kernel<<<big ? 5040 : 2736, 256, 0, stream>>>(images, Y, ctok, pos, X,
                                                         w_map, Wmb, w1, W1r, w2, W2r);
  gemm_embed<<<600, 256, 0, stream>>>(Y, Wmb, b_map, pos, X);

  for (int l = 0; l < 12; ++l) {
    unsigned short* W1p = big ? W1r + l * L1 : W1r;
    unsigned short* W2p = big ? W2r + l * L1 : W2r;
    if (l == 0)
      ln_kernel<0><<<800, 256, 0, stream>>>(X, nullptr, nullptr,
                                            ln1w + l * 768, ln1b + l * 768, Y,
                                            nullptr, nullptr, nullptr, nullptr);
    else
      ln_kernel<2><<<800, 256, 0, stream>>>(X, Pp, b2 + (l - 1) * 768,
                                            ln1w + l * 768, ln1b + l * 768, Y,
                                            nullptr, nullptr, nullptr, nullptr);
    qkvproj_kernel<<<1152, 128, 0, stream>>>(Y,
                                             qw + (size_t)l * 49152, qb + l * 768,
                                             kw + (size_t)l * 49152, kb + l * 768,
                                             vw + (size_t)l * 49152, vb + l * 768,
                                             Qb, Kb2, Vtb);
    attn_kernel<<<2496, 64, 0, stream>>>(Qb, Kb2, Vtb, X);
    // ln2: LN blocks [0,800) + (big, l<11) conversion blocks for layer l+1's weights
    const bool cvt = big && (l < 11);
    ln_kernel<0><<<cvt ? 3104 : 800, 256, 0, stream>>>(X, nullptr, nullptr,
                                                       ln2w + l * 768, ln2b + l * 768, Y,
                                                       cvt ? w1 + (size_t)(l + 1) * L1 : nullptr,
                                                       cvt ? W1r + (size_t)(l + 1) * L1 : nullptr,
                                                       cvt ? w2 + (size_t)(l + 1) * L1 : nullptr,
                                                       cvt ? W2r + (size_t)(l + 1) * L1 : nullptr);
    if (!big)
      convw_kernel<<<2304, 256, 0, stream>>>(w1 + (size_t)l * L1, W1p,
                                             w2 + (size_t)l * L1, W2p, 294912);
    // up: M=3200 N=3072 K=768 -> 25x24=600 blocks; down: split-K2, 25x6x2=300 blocks, NT=48
    gemm4b<1, 24><<<600, 256, 0, stream>>>(Y, W1p, 768, 24, 25, b1 + l * 3072, nullptr, Hb);
    gemm4b<3, 48><<<300, 256, 0, stream>>>(Hb, W2p, 3072, 6, 25, nullptr, Pp, nullptr);
  }
  redfin_kernel<<<2364, 256, 0, stream>>>(X, Pp, b2 + 11 * 768);
}

// Round 3
// 1428.591 us; speedup vs baseline: 1.1020x; 1.1020x over previous
//
#include <hip/hip_runtime.h>
#include <hip/hip_bf16.h>
#include <math.h>

typedef __attribute__((ext_vector_type(4))) float f32x4;
typedef __attribute__((ext_vector_type(8))) __bf16 bf16x8;
typedef __attribute__((ext_vector_type(8))) short short8;
typedef __attribute__((ext_vector_type(4))) unsigned short us4;
typedef __attribute__((ext_vector_type(8))) unsigned short us8;

#define B_    16
#define SEQ_  197
#define TOK_  3152      // 16*197
#define HID_  768
#define MPAD_ 3200      // padded token rows
#define NP_   3136      // 16*196 patch rows
#define DFF_  3072
#define PSZ_  (MPAD_ * HID_)   // one partial buffer, elements (bf16)
#define QKVP_ 14336            // per-(b,h) plane: 224*64 shorts
#define BHN_  192              // 16*12

__device__ __forceinline__ unsigned short f2bf(float x) {
  union { float f; unsigned int u; } v; v.f = x;
  unsigned int r = v.u + 0x7fffu + ((v.u >> 16) & 1u);
  return (unsigned short)(r >> 16);
}

__device__ __forceinline__ float bf2f(unsigned short u) {
  union { unsigned int i; float f; } v; v.i = ((unsigned int)u) << 16; return v.f;
}

__device__ __forceinline__ f32x4 mfma16(bf16x8 a, bf16x8 b, f32x4 c) {
  return __builtin_amdgcn_mfma_f32_16x16x32_bf16(a, b, c, 0, 0, 0);
}

__device__ __forceinline__ void cp16(const void* g, void* l) {
  __builtin_amdgcn_global_load_lds((__attribute__((address_space(1))) void*)(g),
                                   (__attribute__((address_space(3))) void*)(l),
                                   16, 0, 0);
}

// fast gelu: x*sigmoid(x*(1.59577+0.0713548*x^2))
__device__ __forceinline__ float gelu_f(float x) {
  float y = x * (1.5957691216f + 0.0713548162f * x * x);
  float e = __expf(y);
  float r = 1.0f / (1.0f + e);     // e=inf -> r=0 -> g=x ; e=0 -> r=1 -> g=0
  return x - x * r;
}

// convert chunk c (8 floats) of s into d
__device__ __forceinline__ void conv8(const float* __restrict__ s, unsigned short* __restrict__ d, int c) {
  const float* sp = s + (size_t)c * 8;
  f32x4 v0 = *(const f32x4*)sp;
  f32x4 v1 = *(const f32x4*)(sp + 4);
  us8 o;
  o[0] = f2bf(v0[0]); o[1] = f2bf(v0[1]); o[2] = f2bf(v0[2]); o[3] = f2bf(v0[3]);
  o[4] = f2bf(v1[0]); o[5] = f2bf(v1[1]); o[6] = f2bf(v1[2]); o[7] = f2bf(v1[3]);
  *(us8*)(d + (size_t)c * 8) = o;
}

// ---------------- fused patchify + cls + wmap-conv + (big) layer-0 MLP weight conv
// blocks [0,2400): patchify  [2400,2448): cls  [2448,2736): wmap conv (73728 chunks)
// blocks [2736,5040): layer-0 w1/w2 conv (1152 blocks each, 294912 chunks)
__global__ __launch_bounds__(256) void patchcls_kernel(const float* __restrict__ img,
                                                       unsigned short* __restrict__ Pb,
                                                       const float* __restrict__ ct,
                                                       const float* __restrict__ pos,
                                                       float* __restrict__ X,
                                                       const float* __restrict__ wmap,
                                                       unsigned short* __restrict__ Wmb,
                                                       const float* __restrict__ cw1,
                                                       unsigned short* __restrict__ cd1,
                                                       const float* __restrict__ cw2,
                                                       unsigned short* __restrict__ cd2) {
  int bid = blockIdx.x;
  if (bid >= 2736) {          // layer-0 MLP weights
    int bb = bid - 2736;
    const float* s; unsigned short* d;
    if (bb < 1152) { s = cw1; d = cd1; } else { s = cw2; d = cd2; bb -= 1152; }
    conv8(s, d, bb * 256 + threadIdx.x);
    return;
  }
  if (bid >= 2448) {          // w_map conv
    int c = (bid - 2448) * 256 + threadIdx.x;
    conv8(wmap, Wmb, c);
    return;
  }
  if (bid >= 2400) {          // cls rows
    int j = (bid - 2400) * 256 + threadIdx.x;
    if (j < B_ * HID_) {
      int b = j / HID_, t = j - b * HID_;
      X[(size_t)b * SEQ_ * HID_ + t] = ct[t] + pos[t];
    }
    return;
  }
  int gid = bid * 256 + threadIdx.x;              // 3200*192 total
  int m = gid / 192;
  int j4 = (gid - m * 192) * 4;
  us4 o;
  if (m < NP_) {
    int n = m / 196, p = m - n * 196;
    int pi = p / 14, pj = p - pi * 14;
    int c = j4 >> 8, rem = j4 & 255, ph = rem >> 4, pw = rem & 15;
    const float* src = img + (((size_t)(n * 3 + c) * 224 + pi * 16 + ph) * 224 + pj * 16 + pw);
    f32x4 v = *(const f32x4*)src;
    o[0] = f2bf(v[0]); o[1] = f2bf(v[1]); o[2] = f2bf(v[2]); o[3] = f2bf(v[3]);
  } else {
    o[0] = 0; o[1] = 0; o[2] = 0; o[3] = 0;
  }
  *(us4*)(Pb + (size_t)m * HID_ + j4) = o;
}

// ---------------- standalone fp32 -> bf16 conversion (fallback path only)
__global__ __launch_bounds__(256) void convw_kernel(const float* __restrict__ s1, unsigned short* __restrict__ d1,
                                                    const float* __restrict__ s2, unsigned short* __restrict__ d2,
                                                    int nchunks) {
  int half = gridDim.x >> 1;
  int b = blockIdx.x;
  const float* s; unsigned short* d;
  if (b < half) { s = s1; d = d1; } else { s = s2; d = d2; b -= half; }
  int c = b * 256 + threadIdx.x;
  if (c >= nchunks) return;
  conv8(s, d, c);
}

// ---------------- embed GEMM (BT form): 64x64-tile structure, EPI=embed
__global__ __launch_bounds__(256) void gemm_embed(const unsigned short* __restrict__ A,
                                                  const unsigned short* __restrict__ Bw,
                                                  const float* __restrict__ bias,
                                                  const float* __restrict__ pos,
                                                  float* __restrict__ Xout) {
  constexpr int MI = 2, NJ = 2, BM = 64, BN = 64;
  __shared__ unsigned short As[BM * 64];
  __shared__ unsigned short Bs[BN * 64];
  const int tid = threadIdx.x;
  const int w = tid >> 6, lane = tid & 63;
  const int lr = lane & 15, kg = lane >> 4;
  int bid = blockIdx.x;
  int cpx = gridDim.x >> 3;
  int swz = (bid & 7) * cpx + (bid >> 3);
  const int by = swz / 12, bx = swz - by * 12;
  const int m0 = by * BM, n0 = bx * BN;
  const int wr = w >> 1, wc = w & 1;
  const f32x4 z4 = {0.f, 0.f, 0.f, 0.f};
  f32x4 acc[MI][NJ];
#pragma unroll
  for (int i = 0; i < MI; ++i)
#pragma unroll
    for (int j = 0; j < NJ; ++j) acc[i][j] = z4;
  for (int k0 = 0; k0 < 768; k0 += 64) {
#pragma unroll
    for (int is = 0; is < MI; ++is) {
      int chunk = is * 256 + tid;
      int row = chunk >> 3, cc = (chunk & 7) * 8;
      cp16(A + (size_t)(m0 + row) * 768 + k0 + cc, As + is * 2048 + w * 512);
    }
#pragma unroll
    for (int is = 0; is < NJ; ++is) {
      int chunk = is * 256 + tid;
      int row = chunk >> 3, cc = (chunk & 7) * 8;
      cp16(Bw + (size_t)(n0 + row) * 768 + k0 + cc, Bs + is * 2048 + w * 512);
    }
    __syncthreads();
#pragma unroll
    for (int kk = 0; kk < 64; kk += 32) {
      bf16x8 af[MI], bfr[NJ];
#pragma unroll
      for (int i = 0; i < MI; ++i)
        af[i] = *(const bf16x8*)&As[(wr * (BM / 2) + i * 16 + lr) * 64 + kk + kg * 8];
#pragma unroll
      for (int j = 0; j < NJ; ++j)
        bfr[j] = *(const bf16x8*)&Bs[(wc * (BN / 2) + j * 16 + lr) * 64 + kk + kg * 8];
#pragma unroll
      for (int i = 0; i < MI; ++i)
#pragma unroll
        for (int j = 0; j < NJ; ++j)
          acc[i][j] = mfma16(af[i], bfr[j], acc[i][j]);
    }
    __syncthreads();
  }
#pragma unroll
  for (int i = 0; i < MI; ++i) {
    int mbase = m0 + wr * (BM / 2) + i * 16 + kg * 4;
#pragma unroll
    for (int j = 0; j < NJ; ++j) {
      int col = n0 + wc * (BN / 2) + j * 16 + lr;
#pragma unroll
      for (int qr = 0; qr < 4; ++qr) {
        int m = mbase + qr;
        if (m < NP_) {
          int nimg = m / 196;
          int tok = m + nimg + 1;
          int prow = m - nimg * 196 + 1;
          Xout[(size_t)tok * HID_ + col] = acc[i][j][qr] + bias[col] + pos[(size_t)prow * HID_ + col];
        }
      }
    }
  }
}

// ---------------- 128x128-tile 8-wave pipelined GEMM, BK=32, 4 LDS buffers (64KB -> 2 blocks/CU)
// Round-1 proven structure (512 thr, 64x32 wave tile, counted vmcnt) + LDS XOR swizzle:
// 16B-unit u -> u ^ ((row>>1)&3), pre-swizzled GLOBAL source (linear LDS dest, rule #21)
// + swizzled ds_read offsets. Verified: 8-way conflict -> 0 (round-2 PMC).
template<int EPI, int NT>
__global__ __launch_bounds__(512, 2) void gemm4b(const unsigned short* __restrict__ A,
                                                 const unsigned short* __restrict__ Bw,
                                                 int ldk, int gx, int gy,
                                                 const float* __restrict__ bias,
                                                 unsigned short* __restrict__ Pout,
                                                 unsigned short* __restrict__ Hout) {
  __shared__ unsigned short lds4[32768];   // 4 buffers x (A 4096 + B 4096 shorts) = 64 KiB
  const int tid = threadIdx.x;
  const int wid = tid >> 6, lane = tid & 63;
  const int lr = lane & 15, kg = lane >> 4;
  const int wm = wid >> 2, wn = wid & 3;           // 2 x 4 waves; wave owns 64 x 32 output
  const int nwg = gridDim.x;
  const int q = nwg >> 3, r = nwg & 7;
  const int xcd = blockIdx.x & 7, idx = blockIdx.x >> 3;
  const int wgid = (xcd < r ? xcd * (q + 1) : r * (q + 1) + (xcd - r) * q) + idx;
  const int bx = wgid % gx;
  const int rest = wgid / gx;
  const int by = rest % gy;
  const int z = rest / gy;
  const int m0 = by * 128, n0 = bx * 128;
  const unsigned short* Abase = A + (size_t)m0 * ldk + z * (NT * 32);
  const unsigned short* Bbase = Bw + (size_t)n0 * ldk + z * (NT * 32);

  // chunk = tid: row = tid>>2 (0..127), 16B-unit u = tid&3. LDS dst linear;
  // global source k-column pre-swizzled by row: u ^ ((row>>1)&3).
  const int ra = tid >> 2, ua = tid & 3;
  const int sk = (ua ^ ((ra >> 1) & 3)) * 8;       // shorts
  const int wbase = wid * 512;                     // wave-uniform LDS dst (shorts); HW adds lane*16B

  // prologue: issue tiles 0,1,2 (6 cp16/thread outstanding)
#pragma unroll
  for (int t = 0; t < 3; ++t) {
    unsigned short* lb = lds4 + t * 8192;
    cp16(Abase + (size_t)ra * ldk + sk + t * 32, lb + wbase);
    cp16(Bbase + (size_t)ra * ldk + sk + t * 32, lb + 4096 + wbase);
  }

  // per-lane swizzled fragment-read offsets (shorts), hoisted
  int offA[4], offB[2];
#pragma unroll
  for (int i = 0; i < 4; ++i) {
    int rr = wm * 64 + i * 16 + lr;
    offA[i] = rr * 32 + ((kg ^ ((rr >> 1) & 3)) * 8);
  }
#pragma unroll
  for (int j = 0; j < 2; ++j) {
    int rr = wn * 32 + j * 16 + lr;
    offB[j] = rr * 32 + ((kg ^ ((rr >> 1) & 3)) * 8);
  }

  const f32x4 z4 = {0.f, 0.f, 0.f, 0.f};
  f32x4 acc[4][2];
#pragma unroll
  for (int i = 0; i < 4; ++i)
#pragma unroll
    for (int j = 0; j < 2; ++j) acc[i][j] = z4;

#pragma unroll 1
  for (int k = 0; k < NT; ++k) {
    // gate: tile k resident; tiles k+1,k+2 (4 loads/thread) may stay in flight
    asm volatile("s_waitcnt vmcnt(4)" ::: "memory");
    __builtin_amdgcn_s_barrier();
    __builtin_amdgcn_sched_barrier(0);
    const unsigned short* lp = lds4 + (k & 3) * 8192;
    const int tn = k + 3;
    const int ts = (tn >= NT) ? tn - NT : tn;      // wrapped tail prefetch (harmless reissue)
    unsigned short* tb = lds4 + (tn & 3) * 8192;   // == (k-1)&3: readers done before this gate
    bf16x8 af[4], bfr[2];
#pragma unroll
    for (int i = 0; i < 4; ++i)
      af[i] = *(const bf16x8*)(lp + offA[i]);
#pragma unroll
    for (int j = 0; j < 2; ++j)
      bfr[j] = *(const bf16x8*)(lp + 4096 + offB[j]);
    cp16(Abase + (size_t)ra * ldk + sk + ts * 32, tb + wbase);
    cp16(Bbase + (size_t)ra * ldk + sk + ts * 32, tb + 4096 + wbase);
    __builtin_amdgcn_s_barrier();
    __builtin_amdgcn_s_setprio(1);
#pragma unroll
    for (int i = 0; i < 4; ++i)
#pragma unroll
      for (int j = 0; j < 2; ++j) acc[i][j] = mfma16(af[i], bfr[j], acc[i][j]);
    __builtin_amdgcn_s_setprio(0);
    // next iteration's gate barrier closes this tile
  }

  // epilogue
#pragma unroll
  for (int i = 0; i < 4; ++i) {
    int mbase = m0 + wm * 64 + i * 16 + kg * 4;
#pragma unroll
    for (int j = 0; j < 2; ++j) {
      int col = n0 + wn * 32 + j * 16 + lr;
      float bv = (EPI == 1) ? bias[col] : 0.f;
#pragma unroll
      for (int qr = 0; qr < 4; ++qr) {
        int m = mbase + qr;
        if (m < TOK_) {
          float v = acc[i][j][qr];
          if (EPI == 1) {
            Hout[(size_t)m * 3072 + col] = f2bf(gelu_f(v + bv));
          } else {
            Pout[(size_t)z * PSZ_ + (size_t)m * 768 + col] = f2bf(v);
          }
        }
      }
    }
  }
}

// ---------------- LayerNorm; MODE 0: plain  2: X+=P0..P3(bf16)+pb ; writes Y bf16
// blocks >= 800 (if launched): convert cw1->cd1 (1152 blocks) then cw2->cd2 (1152 blocks)
template<int MODE>
__global__ __launch_bounds__(256) void ln_kernel(float* __restrict__ X,
                                                 const unsigned short* __restrict__ P, const float* __restrict__ pb,
                                                 const float* __restrict__ gw, const float* __restrict__ gb,
                                                 unsigned short* __restrict__ Y,
                                                 const float* __restrict__ cw1, unsigned short* __restrict__ cd1,
                                                 const float* __restrict__ cw2, unsigned short* __restrict__ cd2) {
  int bb = (int)blockIdx.x - 800;
  if (bb >= 0) {              // weight-conversion blocks (next layer's w1/w2)
    const float* s; unsigned short* d;
    if (bb < 1152) { s = cw1; d = cd1; } else { s = cw2; d = cd2; bb -= 1152; }
    conv8(s, d, bb * 256 + threadIdx.x);
    return;
  }
  int row = blockIdx.x * 4 + (threadIdx.x >> 6);
  int lane = threadIdx.x & 63;
  if (row >= MPAD_) return;
  size_t base = (size_t)row * HID_;
  if (row >= TOK_) {
    us4 zz; zz[0] = 0; zz[1] = 0; zz[2] = 0; zz[3] = 0;
#pragma unroll
    for (int i = 0; i < 3; ++i) *(us4*)(Y + base + i * 256 + lane * 4) = zz;
    return;
  }
  f32x4 xv[3];
  float s1 = 0.f, s2 = 0.f;
#pragma unroll
  for (int i = 0; i < 3; ++i) {
    int cb = i * 256 + lane * 4;
    f32x4 v = *(const f32x4*)(X + base + cb);
    if (MODE == 2) {
      const unsigned short* pp = P + base + cb;
      us4 p0 = *(const us4*)(pp);
      us4 p1 = *(const us4*)(pp + PSZ_);
      us4 p2 = *(const us4*)(pp + 2 * (size_t)PSZ_);
      us4 p3 = *(const us4*)(pp + 3 * (size_t)PSZ_);
      f32x4 bb2 = *(const f32x4*)(pb + cb);
#pragma unroll
      for (int e = 0; e < 4; ++e)
        v[e] += bf2f(p0[e]) + bf2f(p1[e]) + bf2f(p2[e]) + bf2f(p3[e]) + bb2[e];
      *(f32x4*)(X + base + cb) = v;
    }
    xv[i] = v;
    s1 += v[0] + v[1] + v[2] + v[3];
    s2 += v[0] * v[0] + v[1] * v[1] + v[2] * v[2] + v[3] * v[3];
  }
#pragma unroll
  for (int d = 1; d < 64; d <<= 1) {
    s1 += __shfl_xor(s1, d);
    s2 += __shfl_xor(s2, d);
  }
  float mu = s1 * (1.f / 768.f);
  float var = s2 * (1.f / 768.f) - mu * mu;
  float rs = rsqrtf(var + 1e-5f);
#pragma unroll
  for (int i = 0; i < 3; ++i) {
    int cb = i * 256 + lane * 4;
    us4 o;
#pragma unroll
    for (int e = 0; e < 4; ++e)
      o[e] = f2bf((xv[i][e] - mu) * rs * gw[cb + e] + gb[cb + e]);
    *(us4*)(Y + base + cb) = o;
  }
}

// ---------------- final split-K reduce: X[m] += P0..P3(bf16) + b2   (after layer 11)
__global__ __launch_bounds__(256) void redfin_kernel(float* __restrict__ X, const unsigned short* __restrict__ P,
                                                     const float* __restrict__ b2) {
  int i = blockIdx.x * 256 + threadIdx.x;     // TOK_*192
  if (i >= TOK_ * 192) return;
  int m = i / 192, c4 = (i - m * 192) * 4;
  size_t off = (size_t)m * HID_ + c4;
  f32x4 v = *(const f32x4*)(X + off);
  const unsigned short* pp = P + off;
  us4 p0 = *(const us4*)(pp);
  us4 p1 = *(const us4*)(pp + PSZ_);
  us4 p2 = *(const us4*)(pp + 2 * (size_t)PSZ_);
  us4 p3 = *(const us4*)(pp + 3 * (size_t)PSZ_);
  f32x4 bb = *(const f32x4*)(b2 + c4);
#pragma unroll
  for (int e = 0; e < 4; ++e)
    v[e] += bf2f(p0[e]) + bf2f(p1[e]) + bf2f(p2[e]) + bf2f(p3[e]) + bb[e];
  *(f32x4*)(X + off) = v;
}

// ---------------- load 64x64 fp32 weight as bf16 B-fragments (8 x bf16x8 per lane)
__device__ __forceinline__ void loadw_frags(const float* __restrict__ W, int lr, int kg, bf16x8* wf) {
#pragma unroll
  for (int j = 0; j < 4; ++j)
#pragma unroll
    for (int kk = 0; kk < 2; ++kk) {
      const float* wp = W + (j * 16 + lr) * 64 + kk * 32 + kg * 8;
      f32x4 w0 = *(const f32x4*)wp;
      f32x4 w1 = *(const f32x4*)(wp + 4);
      short8 t;
      t[0] = (short)f2bf(w0[0]); t[1] = (short)f2bf(w0[1]); t[2] = (short)f2bf(w0[2]); t[3] = (short)f2bf(w0[3]);
      t[4] = (short)f2bf(w1[0]); t[5] = (short)f2bf(w1[1]); t[6] = (short)f2bf(w1[2]); t[7] = (short)f2bf(w1[3]);
      wf[j * 2 + kk] = __builtin_bit_cast(bf16x8, t);
    }
}

// ---------------- QKV projection: grid 1152 = bh(192) x proj(3) x half(2); 2 waves/block.
// Writes bf16 Q (x0.125) and K row-major [224][64], V transposed [64][224] per (b,h).
// V columns >=197 are zeroed (PV loop reads up to col 223); K rows 197..207 are
// finite-garbage (masked in attn); Q rows >=197 masked at the X write.
__global__ __launch_bounds__(128) void qkvproj_kernel(const unsigned short* __restrict__ Y,
                                                      const float* __restrict__ qw, const float* __restrict__ qb,
                                                      const float* __restrict__ kw, const float* __restrict__ kb,
                                                      const float* __restrict__ vw, const float* __restrict__ vb,
                                                      unsigned short* __restrict__ Qo,
                                                      unsigned short* __restrict__ Ko,
                                                      unsigned short* __restrict__ Vto) {
  const int blk = blockIdx.x;
  const int half = blk & 1;
  const int bp = blk >> 1;                 // 576 = bh*3 + p
  const int p = bp % 3, bh = bp / 3;
  const int b = bh / 12, h = bh - b * 12;
  const int wv = threadIdx.x >> 6, lane = threadIdx.x & 63;
  const int lr = lane & 15, kg = lane >> 4;
  const int ws = half * 2 + wv;            // 0..3 : tile stride-4 owner
  const float* W; const float* bs; unsigned short* out;
  if (p == 0)      { W = qw + h * 4096; bs = qb + h * 64; out = Qo; }
  else if (p == 1) { W = kw + h * 4096; bs = kb + h * 64; out = Ko; }
  else             { W = vw + h * 4096; bs = vb + h * 64; out = Vto; }
  const float scale = (p == 0) ? 0.125f : 1.0f;
  bf16x8 wf[8];
  loadw_frags(W, lr, kg, wf);
  float bj[4];
#pragma unroll
  for (int j = 0; j < 4; ++j) bj[j] = bs[j * 16 + lr];
  out += (size_t)bh * QKVP_;
  const f32x4 z4 = {0.f, 0.f, 0.f, 0.f};
  const short8 zs = {0, 0, 0, 0, 0, 0, 0, 0};
#pragma unroll
  for (int i = 0; i < 4; ++i) {
    int t = ws + 4 * i;
    if (t < 14) {
      int s = t * 16 + lr;
      bf16x8 a0 = __builtin_bit_cast(bf16x8, zs), a1 = a0;
      if (s < SEQ_) {
        const unsigned short* yp = Y + (size_t)(b * SEQ_ + s) * HID_ + h * 64 + kg * 8;
        a0 = *(const bf16x8*)yp;
        a1 = *(const bf16x8*)(yp + 32);
      }
      f32x4 acc[4] = {z4, z4, z4, z4};
#pragma unroll
      for (int j = 0; j < 4; ++j) {
        acc[j] = mfma16(a0, wf[j * 2 + 0], acc[j]);
        acc[j] = mfma16(a1, wf[j * 2 + 1], acc[j]);
      }
      if (p == 2) {
#pragma unroll
        for (int j = 0; j < 4; ++j) {
          us4 pk;
#pragma unroll
          for (int qr = 0; qr < 4; ++qr) {
            int srow = t * 16 + kg * 4 + qr;
            pk[qr] = (srow < SEQ_) ? f2bf(acc[j][qr] + bj[j]) : (unsigned short)0;
          }
          *(us4*)&out[(j * 16 + lr) * 224 + t * 16 + kg * 4] = pk;
        }
      } else {
#pragma unroll
        for (int j = 0; j < 4; ++j)
#pragma unroll
          for (int qr = 0; qr < 4; ++qr) {
            int row = t * 16 + kg * 4 + qr;
            out[row * 64 + j * 16 + lr] = f2bf((acc[j][qr] + bj[j]) * scale);
          }
      }
    }
  }
}

// ---------------- attention: grid 2496 = bh(192) x qtile(13); 1 wave/block, 7.4 KiB LDS.
// Same math as the old fused phase C; K/V read from L2-resident global planes.
__global__ __launch_bounds__(64) void attn_kernel(const unsigned short* __restrict__ Qb,
                                                  const unsigned short* __restrict__ Kb,
                                                  const unsigned short* __restrict__ Vtb,
                                                  float* __restrict__ X) {
  __shared__ unsigned short plds[16 * 232];
  const int blk = blockIdx.x;
  const int qt = blk % 13, bh = blk / 13;
  const int b = bh / 12, h = bh - b * 12;
  const int lane = threadIdx.x;
  const int lr = lane & 15, kg = lane >> 4;
  const f32x4 z4 = {0.f, 0.f, 0.f, 0.f};
  const unsigned short* Qp = Qb + (size_t)bh * QKVP_;
  const unsigned short* Kp = Kb + (size_t)bh * QKVP_;
  const unsigned short* Vp = Vtb + (size_t)bh * QKVP_;
  // zero pad columns 208..223 of P (PV loop kt=6 reads them)
  {
    int rr = lane >> 2, c0 = 208 + (lane & 3) * 4;
    us4 zz; zz[0] = 0; zz[1] = 0; zz[2] = 0; zz[3] = 0;
    *(us4*)&plds[rr * 232 + c0] = zz;
  }
  bf16x8 aq0 = *(const bf16x8*)&Qp[(qt * 16 + lr) * 64 + kg * 8];
  bf16x8 aq1 = *(const bf16x8*)&Qp[(qt * 16 + lr) * 64 + 32 + kg * 8];
  f32x4 s[13];
#pragma unroll
  for (int nt = 0; nt < 13; ++nt) {
    const unsigned short* kp = Kp + (nt * 16 + lr) * 64 + kg * 8;
    bf16x8 b0 = *(const bf16x8*)kp;
    bf16x8 b1 = *(const bf16x8*)(kp + 32);
    f32x4 acc = mfma16(aq0, b0, z4);
    s[nt] = mfma16(aq1, b1, acc);
  }
#pragma unroll
  for (int qr = 0; qr < 4; ++qr) {
    float mx = -1e30f;
#pragma unroll
    for (int nt = 0; nt < 13; ++nt) {
      float v = (nt == 12 && lr >= 5) ? -1e30f : s[nt][qr];
      mx = fmaxf(mx, v);
    }
    mx = fmaxf(mx, __shfl_xor(mx, 1));
    mx = fmaxf(mx, __shfl_xor(mx, 2));
    mx = fmaxf(mx, __shfl_xor(mx, 4));
    mx = fmaxf(mx, __shfl_xor(mx, 8));
    float sum = 0.f;
#pragma unroll
    for (int nt = 0; nt < 13; ++nt) {
      float e = (nt == 12 && lr >= 5) ? 0.f : __expf(s[nt][qr] - mx);
      s[nt][qr] = e;
      sum += e;
    }
    sum += __shfl_xor(sum, 1);
    sum += __shfl_xor(sum, 2);
    sum += __shfl_xor(sum, 4);
    sum += __shfl_xor(sum, 8);
    float inv = 1.f / sum;
#pragma unroll
    for (int nt = 0; nt < 13; ++nt)
      plds[(kg * 4 + qr) * 232 + nt * 16 + lr] = f2bf(s[nt][qr] * inv);
  }
  asm volatile("s_waitcnt lgkmcnt(0)" ::: "memory");
  __builtin_amdgcn_sched_barrier(0);
  f32x4 ao[4] = {z4, z4, z4, z4};
#pragma unroll
  for (int kt = 0; kt < 7; ++kt) {
    bf16x8 pa = *(const bf16x8*)&plds[lr * 232 + kt * 32 + kg * 8];
#pragma unroll
    for (int j = 0; j < 4; ++j) {
      bf16x8 bv = *(const bf16x8*)&Vp[(j * 16 + lr) * 224 + kt * 32 + kg * 8];
      ao[j] = mfma16(pa, bv, ao[j]);
    }
  }
#pragma unroll
  for (int j = 0; j < 4; ++j)
#pragma unroll
    for (int qr = 0; qr < 4; ++qr) {
      int ss = qt * 16 + kg * 4 + qr;
      if (ss < SEQ_) {
        size_t xi = (size_t)(b * SEQ_ + ss) * HID_ + h * 64 + j * 16 + lr;
        X[xi] += ao[j][qr];
      }
    }
}

extern "C" void kernel_launch(void* const* d_in, const int* in_sizes, int n_in,
                              void* d_out, int out_size, void* d_ws, size_t ws_size,
                              hipStream_t stream) {
  const float* images = (const float*)d_in[0];
  const float* w_map  = (const float*)d_in[1];
  const float* b_map  = (const float*)d_in[2];
  const float* ctok   = (const float*)d_in[3];
  const float* pos    = (const float*)d_in[4];
  const float* qw   = (const float*)d_in[5];
  const float* qb   = (const float*)d_in[6];
  const float* kw   = (const float*)d_in[7];
  const float* kb   = (const float*)d_in[8];
  const float* vw   = (const float*)d_in[9];
  const float* vb   = (const float*)d_in[10];
  const float* ln1w = (const float*)d_in[11];
  const float* ln1b = (const float*)d_in[12];
  const float* ln2w = (const float*)d_in[13];
  const float* ln2b = (const float*)d_in[14];
  const float* w1   = (const float*)d_in[15];
  const float* b1   = (const float*)d_in[16];
  const float* w2   = (const float*)d_in[17];
  const float* b2   = (const float*)d_in[18];

  float* X = (float*)d_out;   // residual stream lives in d_out: [16*197][768] fp32

  unsigned short* Y    = (unsigned short*)d_ws;                 // [3200][768] bf16 (also patch buffer)
  unsigned short* Wmb  = Y + (size_t)MPAD_ * HID_;              // 768*768
  unsigned short* Hb   = Wmb + (size_t)768 * 768;               // [3200][3072] bf16
  unsigned short* Pp   = Hb + (size_t)MPAD_ * DFF_;             // 4x [3200][768] bf16 split-K partials
  unsigned short* Wr   = Pp + 4 * (size_t)PSZ_;                 // converted MLP weights

  // Q/K/Vt bf16 planes alias the Hb region (dead between gemm-down(l-1) and gemm-up(l)):
  // 3 * 192 * 14336 shorts = 8,257,536 <= 9,830,400 (Hb size). Stream-ordered, no hazard.
  unsigned short* Qb  = Hb;
  unsigned short* Kb2 = Hb + (size_t)BHN_ * QKVP_;
  unsigned short* Vtb = Hb + 2 * (size_t)BHN_ * QKVP_;

  // big path: all 12 layers' w1+w2 pre-converted (fused into patchcls / ln launches)
  const size_t L1 = (size_t)DFF_ * HID_;          // 2,359,296 per layer
  const size_t need = ((size_t)MPAD_ * HID_ + (size_t)768 * 768 + (size_t)MPAD_ * DFF_ +
                       4 * (size_t)PSZ_ + 24 * L1) * 2;
  const bool big = ws_size >= need;
  unsigned short* W1r = Wr;
  unsigned short* W2r = Wr + (big ? 12 * L1 : L1);

  // ---- prologue: patchify + cls + wmap conv + (big) layer-0 MLP weight conv
  patchcls_kernel<<<big ? 5040 : 2736, 256, 0, stream>>>(images, Y, ctok, pos, X,
                                                         w_map, Wmb, w1, W1r, w2, W2r);
  gemm_embed<<<600, 256, 0, stream>>>(Y, Wmb, b_map, pos, X);

  for (int l = 0; l < 12; ++l) {
    unsigned short* W1p = big ? W1r + l * L1 : W1r;
    unsigned short* W2p = big ? W2r + l * L1 : W2r;
    if (l == 0)
      ln_kernel<0><<<800, 256, 0, stream>>>(X, nullptr, nullptr,
                                            ln1w + l * 768, ln1b + l * 768, Y,
                                            nullptr, nullptr, nullptr, nullptr);
    else
      ln_kernel<2><<<800, 256, 0, stream>>>(X, Pp, b2 + (l - 1) * 768,
                                            ln1w + l * 768, ln1b + l * 768, Y,
                                            nullptr, nullptr, nullptr, nullptr);
    qkvproj_kernel<<<1152, 128, 0, stream>>>(Y,
                                             qw + (size_t)l * 49152, qb + l * 768,
                                             kw + (size_t)l * 49152, kb + l * 768,
                                             vw + (size_t)l * 49152, vb + l * 768,
                                             Qb, Kb2, Vtb);
    attn_kernel<<<2496, 64, 0, stream>>>(Qb, Kb2, Vtb, X);
    // ln2: LN blocks [0,800) + (big, l<11) conversion blocks for layer l+1's weights
    const bool cvt = big && (l < 11);
    ln_kernel<0><<<cvt ? 3104 : 800, 256, 0, stream>>>(X, nullptr, nullptr,
                                                       ln2w + l * 768, ln2b + l * 768, Y,
                                                       cvt ? w1 + (size_t)(l + 1) * L1 : nullptr,
                                                       cvt ? W1r + (size_t)(l + 1) * L1 : nullptr,
                                                       cvt ? w2 + (size_t)(l + 1) * L1 : nullptr,
                                                       cvt ? W2r + (size_t)(l + 1) * L1 : nullptr);
    if (!big)
      convw_kernel<<<2304, 256, 0, stream>>>(w1 + (size_t)l * L1, W1p,
                                             w2 + (size_t)l * L1, W2p, 294912);
    // up: M=3200 N=3072 K=768 -> 25x24=600 blocks; down: split-K4, 25x6x4=600 blocks, NT=24
    gemm4b<1, 24><<<600, 512, 0, stream>>>(Y, W1p, 768, 24, 25, b1 + l * 3072, nullptr, Hb);
    gemm4b<3, 24><<<600, 512, 0, stream>>>(Hb, W2p, 3072, 6, 25, nullptr, Pp, nullptr);
  }
  redfin_kernel<<<2364, 256, 0, stream>>>(X, Pp, b2 + 11 * 768);
}